// Round 1
// baseline (187.548 us; speedup 1.0000x reference)
//
#include <hip/hip_runtime.h>
#include <hip/hip_bf16.h>

#define NNODE 50000
#define MTOT  100000   // 2*NNODE rows
#define DIMK  512      // concat K: [Z | Zavg]
#define NF    256
#define KNB   10

typedef unsigned short u16;
typedef float f32x4 __attribute__((ext_vector_type(4)));
typedef short bf16x8 __attribute__((ext_vector_type(8)));

__device__ __forceinline__ u16 f2bf(float f) {
    unsigned u = __builtin_bit_cast(unsigned, f);
    unsigned r = (u + 0x7fffu + ((u >> 16) & 1u)) >> 16;
    return (u16)r;
}
__device__ __forceinline__ float bf2f(u16 h) {
    unsigned u = ((unsigned)h) << 16;
    return __builtin_bit_cast(float, u);
}
__device__ __forceinline__ void gload_lds16(const void* g, void* l) {
    __builtin_amdgcn_global_load_lds(
        (const __attribute__((address_space(1))) unsigned int*)g,
        (__attribute__((address_space(3))) unsigned int*)l, 16, 0, 0);
}

// ---- kernel 1: W^T cast: WT[n][k] = bf16( k<256 ? Wr[k][n] : Wnr[k-256][n] )
__global__ __launch_bounds__(256) void cast_w(const float* __restrict__ Wr,
                                              const float* __restrict__ Wnr,
                                              u16* __restrict__ WT) {
    int id = blockIdx.x * 256 + threadIdx.x;   // 131072 total
    int n = id >> 9;        // 0..255
    int k = id & 511;       // 0..511
    float v = (k < 256) ? Wr[(size_t)k * 256 + n] : Wnr[(size_t)(k - 256) * 256 + n];
    WT[(size_t)n * 512 + k] = f2bf(v);
}

// ---- kernel 2: cast Z1/Z2 f32 -> bf16 into Zcat[m][0:256]
__global__ __launch_bounds__(256) void cast_z(const float* __restrict__ Z1,
                                              const float* __restrict__ Z2,
                                              u16* __restrict__ Zcat) {
    unsigned id = blockIdx.x * 256 + threadIdx.x;  // 3,200,000 total (8 elems each)
    int m = id >> 5;
    int d = (id & 31) << 3;
    const float* src = (m < NNODE) ? (Z1 + (size_t)m * 256 + d)
                                   : (Z2 + (size_t)(m - NNODE) * 256 + d);
    float4 a = *(const float4*)src;
    float4 b = *(const float4*)(src + 4);
    uint4 o;
    o.x = (unsigned)f2bf(a.x) | ((unsigned)f2bf(a.y) << 16);
    o.y = (unsigned)f2bf(a.z) | ((unsigned)f2bf(a.w) << 16);
    o.z = (unsigned)f2bf(b.x) | ((unsigned)f2bf(b.y) << 16);
    o.w = (unsigned)f2bf(b.z) | ((unsigned)f2bf(b.w) << 16);
    *(uint4*)(Zcat + (size_t)m * DIMK + d) = o;
}

// ---- kernel 3: gather+average neighbor Z rows into Zcat[m][256:512]
__global__ __launch_bounds__(256) void gather_k(const int* __restrict__ n1,
                                                const int* __restrict__ n2,
                                                u16* __restrict__ Zcat) {
    int g = blockIdx.x * 4 + (threadIdx.x >> 6);   // node id, 0..99999
    int lane = threadIdx.x & 63;
    int p = (g >= NNODE);
    int i = p ? (g - NNODE) : g;
    const int* nb = (p ? n2 : n1) + (size_t)i * KNB;
    float acc0 = 0.f, acc1 = 0.f, acc2 = 0.f, acc3 = 0.f;
    int cnt = 0;
    #pragma unroll
    for (int k = 0; k < KNB; ++k) {
        int idx = nb[k];
        if (idx > -1) {
            ++cnt;
            const u16* row = Zcat + ((size_t)(p * NNODE + idx)) * DIMK + lane * 4;
            ushort4 v = *(const ushort4*)row;
            acc0 += bf2f(v.x); acc1 += bf2f(v.y); acc2 += bf2f(v.z); acc3 += bf2f(v.w);
        }
    }
    float s = 1.0f / (float)(cnt > 0 ? cnt : 1);
    ushort4 o;
    o.x = f2bf(acc0 * s); o.y = f2bf(acc1 * s); o.z = f2bf(acc2 * s); o.w = f2bf(acc3 * s);
    *(ushort4*)(Zcat + (size_t)g * DIMK + 256 + lane * 4) = o;
}

// ---- kernel 4: GEMM out = relu(Zcat @ WT^T), M=100000, K=512, N=256
// 128x128 tile, BK=64, 256 thr = 4 waves (2x2), each wave 64x64 = 4x4 frags
__global__ __launch_bounds__(256, 2) void gemm_k(const u16* __restrict__ A,   // [MTOT][512]
                                                 const u16* __restrict__ BT,  // [256][512]
                                                 float* __restrict__ C) {
    __shared__ u16 sA[128 * 64];
    __shared__ u16 sB[128 * 64];
    const int m0 = blockIdx.x * 128;
    const int n0 = blockIdx.y * 128;
    const int t = threadIdx.x;
    const int lane = t & 63;
    const int w = t >> 6;
    const int wr = w >> 1, wc = w & 1;

    f32x4 acc[4][4] = {};

    for (int kt = 0; kt < DIMK; kt += 64) {
        // stage A tile [128 rows][64 k] (linear LDS, 16B/lane chunks)
        #pragma unroll
        for (int r = 0; r < 4; ++r) {
            int c = r * 256 + t;          // chunk 0..1023
            int row = c >> 3;             // 0..127
            int kc = c & 7;               // 16B sub-chunk
            int grow = m0 + row;
            if (grow >= MTOT) grow = MTOT - 1;      // clamp; results guarded on store
            const u16* src = A + (size_t)grow * DIMK + kt + kc * 8;
            gload_lds16(src, &sA[c * 8]);
        }
        // stage B tile [128 cols][64 k]
        #pragma unroll
        for (int r = 0; r < 4; ++r) {
            int c = r * 256 + t;
            int row = c >> 3;             // output-col within tile
            int kc = c & 7;
            const u16* src = BT + (size_t)(n0 + row) * DIMK + kt + kc * 8;
            gload_lds16(src, &sB[c * 8]);
        }
        asm volatile("s_waitcnt vmcnt(0)");
        __syncthreads();

        #pragma unroll
        for (int kk = 0; kk < 64; kk += 32) {
            bf16x8 af[4], bf[4];
            int kq = kk + ((lane >> 4) << 3);   // 8 contiguous k per lane
            #pragma unroll
            for (int i = 0; i < 4; ++i) {
                int row = wr * 64 + i * 16 + (lane & 15);
                af[i] = *(const bf16x8*)&sA[row * 64 + kq];
            }
            #pragma unroll
            for (int j = 0; j < 4; ++j) {
                int col = wc * 64 + j * 16 + (lane & 15);
                bf[j] = *(const bf16x8*)&sB[col * 64 + kq];
            }
            #pragma unroll
            for (int i = 0; i < 4; ++i)
                #pragma unroll
                for (int j = 0; j < 4; ++j)
                    acc[i][j] = __builtin_amdgcn_mfma_f32_16x16x32_bf16(af[i], bf[j], acc[i][j], 0, 0, 0);
        }
        __syncthreads();
    }

    // epilogue: relu + store (C/D layout: col = lane&15, row = (lane>>4)*4 + q)
    #pragma unroll
    for (int i = 0; i < 4; ++i) {
        int rbase = m0 + wr * 64 + i * 16 + ((lane >> 4) << 2);
        #pragma unroll
        for (int j = 0; j < 4; ++j) {
            int col = n0 + wc * 64 + j * 16 + (lane & 15);
            #pragma unroll
            for (int q = 0; q < 4; ++q) {
                int row = rbase + q;
                if (row < MTOT) C[(size_t)row * NF + col] = fmaxf(acc[i][j][q], 0.f);
            }
        }
    }
}

extern "C" void kernel_launch(void* const* d_in, const int* in_sizes, int n_in,
                              void* d_out, int out_size, void* d_ws, size_t ws_size,
                              hipStream_t stream) {
    const float* Z1  = (const float*)d_in[0];
    const float* Z2  = (const float*)d_in[1];
    const float* Wr  = (const float*)d_in[2];
    const float* Wnr = (const float*)d_in[3];
    const int*   n1  = (const int*)d_in[4];
    const int*   n2  = (const int*)d_in[5];
    float* out = (float*)d_out;

    u16* WT   = (u16*)d_ws;                 // [256][512]  = 0.26 MB
    u16* Zcat = (u16*)d_ws + 256 * 512;     // [100000][512] = 102.4 MB

    cast_w<<<512, 256, 0, stream>>>(Wr, Wnr, WT);
    cast_z<<<12500, 256, 0, stream>>>(Z1, Z2, Zcat);
    gather_k<<<25000, 256, 0, stream>>>(n1, n2, Zcat);
    gemm_k<<<dim3(782, 2), 256, 0, stream>>>(Zcat, WT, out);
}

// Round 2
// 131.785 us; speedup vs baseline: 1.4231x; 1.4231x over previous
//
#include <hip/hip_runtime.h>
#include <hip/hip_bf16.h>
#include <hip/hip_fp8.h>

#define NNODE 50000
#define MTOT  100000   // 2*NNODE rows
#define DIMK  512      // concat K: [Z | Zavg]
#define NF    256
#define KNB   10

typedef unsigned short u16;
typedef float f32x4 __attribute__((ext_vector_type(4)));
typedef short bf16x8 __attribute__((ext_vector_type(8)));

__device__ __forceinline__ u16 f2bf(float f) {
    unsigned u = __builtin_bit_cast(unsigned, f);
    unsigned r = (u + 0x7fffu + ((u >> 16) & 1u)) >> 16;
    return (u16)r;
}
__device__ __forceinline__ unsigned char f2f8(float f) {
    return (unsigned char)__hip_fp8_e4m3(f).__x;
}
__device__ __forceinline__ float f8tof(unsigned char b) {
    __hip_fp8_e4m3 h;
    h.__x = (__hip_fp8_storage_t)b;
    return (float)h;
}
__device__ __forceinline__ void gload_lds16(const void* g, void* l) {
    __builtin_amdgcn_global_load_lds(
        (const __attribute__((address_space(1))) unsigned int*)g,
        (__attribute__((address_space(3))) unsigned int*)l, 16, 0, 0);
}

// ---- kernel 1: W^T cast: WT[n][k] = bf16( k<256 ? Wr[k][n] : Wnr[k-256][n] )
__global__ __launch_bounds__(256) void cast_w(const float* __restrict__ Wr,
                                              const float* __restrict__ Wnr,
                                              u16* __restrict__ WT) {
    int id = blockIdx.x * 256 + threadIdx.x;   // 131072 total
    int n = id >> 9;        // 0..255
    int k = id & 511;       // 0..511
    float v = (k < 256) ? Wr[(size_t)k * 256 + n] : Wnr[(size_t)(k - 256) * 256 + n];
    WT[(size_t)n * 512 + k] = f2bf(v);
}

// ---- kernel 2: cast Z f32 -> bf16 (Zcat cols 0:256) AND fp8 copy (Z8, gather source)
__global__ __launch_bounds__(256) void cast_z(const float* __restrict__ Z1,
                                              const float* __restrict__ Z2,
                                              u16* __restrict__ Zcat,
                                              unsigned char* __restrict__ Z8) {
    unsigned id = blockIdx.x * 256 + threadIdx.x;  // 3,200,000 total (8 elems each)
    int m = id >> 5;
    int d = (id & 31) << 3;
    const float* src = (m < NNODE) ? (Z1 + (size_t)m * 256 + d)
                                   : (Z2 + (size_t)(m - NNODE) * 256 + d);
    float4 a = *(const float4*)src;
    float4 b = *(const float4*)(src + 4);
    uint4 o;
    o.x = (unsigned)f2bf(a.x) | ((unsigned)f2bf(a.y) << 16);
    o.y = (unsigned)f2bf(a.z) | ((unsigned)f2bf(a.w) << 16);
    o.z = (unsigned)f2bf(b.x) | ((unsigned)f2bf(b.y) << 16);
    o.w = (unsigned)f2bf(b.z) | ((unsigned)f2bf(b.w) << 16);
    *(uint4*)(Zcat + (size_t)m * DIMK + d) = o;
    uint2 o8;
    o8.x = (unsigned)f2f8(a.x) | ((unsigned)f2f8(a.y) << 8) |
           ((unsigned)f2f8(a.z) << 16) | ((unsigned)f2f8(a.w) << 24);
    o8.y = (unsigned)f2f8(b.x) | ((unsigned)f2f8(b.y) << 8) |
           ((unsigned)f2f8(b.z) << 16) | ((unsigned)f2f8(b.w) << 24);
    *(uint2*)(Z8 + (size_t)m * 256 + d) = o8;
}

// ---- kernel 3: gather+average fp8 neighbor rows -> bf16 into Zcat[m][256:512]
__global__ __launch_bounds__(256) void gather_k(const int* __restrict__ n1,
                                                const int* __restrict__ n2,
                                                const unsigned char* __restrict__ Z8,
                                                u16* __restrict__ Zcat) {
    int g = blockIdx.x * 4 + (threadIdx.x >> 6);   // node id, 0..99999
    int lane = threadIdx.x & 63;
    int p = (g >= NNODE);
    int i = p ? (g - NNODE) : g;
    const int* nb = (p ? n2 : n1) + (size_t)i * KNB;
    // hoist all 10 indices (40B, 8B-aligned) for max load ILP
    int idxs[KNB];
    const int2* nb2 = (const int2*)nb;
    #pragma unroll
    for (int k = 0; k < 5; ++k) { int2 v = nb2[k]; idxs[2 * k] = v.x; idxs[2 * k + 1] = v.y; }
    const unsigned char* base = Z8 + (size_t)p * NNODE * 256 + lane * 4;
    float a0 = 0.f, a1 = 0.f, a2 = 0.f, a3 = 0.f;
    int cnt = 0;
    #pragma unroll
    for (int k = 0; k < KNB; ++k) {
        int idx = idxs[k];
        int valid = (idx > -1);
        cnt += valid;
        uchar4 v = *(const uchar4*)(base + (size_t)(valid ? idx : 0) * 256);
        float m = (float)valid;
        a0 += m * f8tof(v.x); a1 += m * f8tof(v.y);
        a2 += m * f8tof(v.z); a3 += m * f8tof(v.w);
    }
    float s = 1.0f / (float)(cnt > 0 ? cnt : 1);
    ushort4 o;
    o.x = f2bf(a0 * s); o.y = f2bf(a1 * s); o.z = f2bf(a2 * s); o.w = f2bf(a3 * s);
    *(ushort4*)(Zcat + (size_t)g * DIMK + 256 + lane * 4) = o;
}

// ---- kernel 4: GEMM out = relu(Zcat @ WT^T), M=100000, K=512, N=256
// 128x256 tile (A read ONCE), BK=64, 512 thr = 8 waves (2Mx4N), wave = 64x64 = 4x4 frags
__global__ __launch_bounds__(512, 2) void gemm_k(const u16* __restrict__ A,   // [MTOT][512]
                                                 const u16* __restrict__ BT,  // [256][512]
                                                 float* __restrict__ C) {
    __shared__ u16 sA[128 * 64];   // 16 KB
    __shared__ u16 sB[256 * 64];   // 32 KB
    const int m0 = blockIdx.x * 128;
    const int t = threadIdx.x;
    const int lane = t & 63;
    const int w = t >> 6;
    const int wr = w >> 2, wc = w & 3;   // 2 x 4 waves

    f32x4 acc[4][4] = {};

    for (int kt = 0; kt < DIMK; kt += 64) {
        // stage A tile [128 rows][64 k]: 1024 x 16B chunks, 2 per thread
        #pragma unroll
        for (int r = 0; r < 2; ++r) {
            int c = r * 512 + t;
            int row = c >> 3;
            int kc = c & 7;
            int grow = m0 + row;
            if (grow >= MTOT) grow = MTOT - 1;      // clamp; results guarded on store
            gload_lds16(A + (size_t)grow * DIMK + kt + kc * 8, &sA[c * 8]);
        }
        // stage B tile [256 cols][64 k]: 2048 x 16B chunks, 4 per thread
        #pragma unroll
        for (int r = 0; r < 4; ++r) {
            int c = r * 512 + t;
            int row = c >> 3;
            int kc = c & 7;
            gload_lds16(BT + (size_t)row * DIMK + kt + kc * 8, &sB[c * 8]);
        }
        asm volatile("s_waitcnt vmcnt(0)");
        __syncthreads();

        #pragma unroll
        for (int kk = 0; kk < 64; kk += 32) {
            bf16x8 af[4], bfr[4];
            int kq = kk + ((lane >> 4) << 3);   // 8 contiguous k per lane
            #pragma unroll
            for (int i = 0; i < 4; ++i) {
                int row = wr * 64 + i * 16 + (lane & 15);
                af[i] = *(const bf16x8*)&sA[row * 64 + kq];
            }
            #pragma unroll
            for (int j = 0; j < 4; ++j) {
                int col = wc * 64 + j * 16 + (lane & 15);
                bfr[j] = *(const bf16x8*)&sB[col * 64 + kq];
            }
            #pragma unroll
            for (int i = 0; i < 4; ++i)
                #pragma unroll
                for (int j = 0; j < 4; ++j)
                    acc[i][j] = __builtin_amdgcn_mfma_f32_16x16x32_bf16(af[i], bfr[j], acc[i][j], 0, 0, 0);
        }
        __syncthreads();
    }

    // epilogue: relu + store (C/D layout: col = lane&15, row = (lane>>4)*4 + q)
    #pragma unroll
    for (int i = 0; i < 4; ++i) {
        int rbase = m0 + wr * 64 + i * 16 + ((lane >> 4) << 2);
        #pragma unroll
        for (int j = 0; j < 4; ++j) {
            int col = wc * 64 + j * 16 + (lane & 15);
            #pragma unroll
            for (int q = 0; q < 4; ++q) {
                int row = rbase + q;
                if (row < MTOT) C[(size_t)row * NF + col] = fmaxf(acc[i][j][q], 0.f);
            }
        }
    }
}

extern "C" void kernel_launch(void* const* d_in, const int* in_sizes, int n_in,
                              void* d_out, int out_size, void* d_ws, size_t ws_size,
                              hipStream_t stream) {
    const float* Z1  = (const float*)d_in[0];
    const float* Z2  = (const float*)d_in[1];
    const float* Wr  = (const float*)d_in[2];
    const float* Wnr = (const float*)d_in[3];
    const int*   n1  = (const int*)d_in[4];
    const int*   n2  = (const int*)d_in[5];
    float* out = (float*)d_out;

    u16* WT   = (u16*)d_ws;                 // [256][512]   = 0.26 MB
    u16* Zcat = (u16*)d_ws + 256 * 512;     // [100000][512] = 102.4 MB
    // fp8 gather source lives in the TAIL of d_out (204.8 MB total): it is fully
    // consumed by gather_k before gemm_k overwrites all of d_out (same stream).
    unsigned char* Z8 = (unsigned char*)d_out + ((size_t)out_size * 4 - (size_t)MTOT * 256);

    cast_w<<<512, 256, 0, stream>>>(Wr, Wnr, WT);
    cast_z<<<12500, 256, 0, stream>>>(Z1, Z2, Zcat, Z8);
    gather_k<<<25000, 256, 0, stream>>>(n1, n2, Z8, Zcat);
    gemm_k<<<782, 512, 0, stream>>>(Zcat, WT, out);
}